// Round 2
// baseline (282.729 us; speedup 1.0000x reference)
//
#include <hip/hip_runtime.h>
#include <math.h>

#define VOL   (128*128*128)   // 2097152 elements per volume
#define PLANE (128*128)       // 16384

// grid partition for mega_kernel
#define LCC_BLOCKS   1024     // 2 pairs x (16 y-tiles x 16 z-tiles x 2 batches)
#define SQ_BLOCKS    1024
#define TV_BLOCKS    256
#define TOTAL_BLOCKS (LCC_BLOCKS + SQ_BLOCKS + 2 * TV_BLOCKS)   // 2560

// ---------------- drain-free barrier ----------------
// LDS release/acquire only: waits lgkmcnt (DS ops) but leaves global-load
// prefetches in flight across the barrier. "memory" clobber pins memory-op
// ordering around the asm so the prefetch issue stays above the barrier.
__device__ __forceinline__ void bar_lds_only() {
    asm volatile("s_waitcnt lgkmcnt(0)" ::: "memory");
    __builtin_amdgcn_s_barrier();
}

// ---------------- reduction helpers ----------------

__device__ __forceinline__ double wave_reduce_d(double v) {
    #pragma unroll
    for (int off = 32; off > 0; off >>= 1)
        v += __shfl_down(v, off, 64);
    return v;
}

__device__ __forceinline__ void block_reduce1_atomic(double a, double* dst) {
    __shared__ double s1[4];
    int lane = threadIdx.x & 63;
    int wave = threadIdx.x >> 6;
    a = wave_reduce_d(a);
    if (lane == 0) s1[wave] = a;
    __syncthreads();
    if (threadIdx.x == 0) {
        double A = s1[0] + s1[1] + s1[2] + s1[3];
        atomicAdd(&dst[0], A);
    }
}

__device__ __forceinline__ void block_reduce2_atomic(double a, double b, double* dst) {
    __shared__ double s2[2][4];
    int lane = threadIdx.x & 63;
    int wave = threadIdx.x >> 6;
    a = wave_reduce_d(a);
    b = wave_reduce_d(b);
    if (lane == 0) { s2[0][wave] = a; s2[1][wave] = b; }
    __syncthreads();
    if (threadIdx.x == 0) {
        atomicAdd(&dst[0], s2[0][0] + s2[0][1] + s2[0][2] + s2[0][3]);
        atomicAdd(&dst[1], s2[1][0] + s2[1][1] + s2[1][2] + s2[1][3]);
    }
}

__device__ __forceinline__ void block_reduce3_atomic(double a, double b, double c, double* dst) {
    __shared__ double s3[3][4];
    int lane = threadIdx.x & 63;
    int wave = threadIdx.x >> 6;
    a = wave_reduce_d(a);
    b = wave_reduce_d(b);
    c = wave_reduce_d(c);
    if (lane == 0) { s3[0][wave] = a; s3[1][wave] = b; s3[2][wave] = c; }
    __syncthreads();
    if (threadIdx.x == 0) {
        atomicAdd(&dst[0], s3[0][0] + s3[0][1] + s3[0][2] + s3[0][3]);
        atomicAdd(&dst[1], s3[1][0] + s3[1][1] + s3[1][2] + s3[1][3]);
        atomicAdd(&dst[2], s3[2][0] + s3[2][1] + s3[2][2] + s3[2][3]);
    }
}

// ---------------- ws layout (doubles) ----------------
// [0]      : sum((F_0g - F_0)^2)
// [1..3]   : lcc pair 0: sum(dg*dp), sum(dg^2), sum(dp^2)
// [4..6]   : lcc pair 1
// [7..8]   : tversky 0: sum(g+p), sum(g*p)
// [9..10]  : tversky 1

__global__ void zero_ws_kernel(double* ws) {
    if (threadIdx.x < 16) ws[threadIdx.x] = 0.0;
}

// ---------------- mega kernel ----------------
// Blocks [0,1024): fused LCC (both pairs).  Tile: x=full 128, y=8, z=8.
//   NEW mapping: g = tid&1 (volume), x = tid>>1. gt/pred threads for the
//   same voxel are ADJACENT LANES -> d_gt*d_pred via __shfl_xor(d,1):
//   no dbuf, no second barrier. One lgkm-only barrier per z-iteration,
//   ybuf double-buffered for WAR safety. Plane z+1 prefetch issued at the
//   top of the iteration (in-flight across the whole iteration).
// Blocks [1024,2048): sqdiff (reg_field_loss numerator)
// Blocks [2048,2560): tversky x2

__global__ __launch_bounds__(256) void mega_kernel(
    const float* __restrict__ F0,  const float* __restrict__ F0g,
    const float* __restrict__ I0,  const float* __restrict__ I0R,
    const float* __restrict__ I1,  const float* __restrict__ I1R,
    const float* __restrict__ S0,  const float* __restrict__ S0g,
    const float* __restrict__ S1,  const float* __restrict__ S1g,
    double* __restrict__ ws)
{
    int b = blockIdx.x;
    int tid = threadIdx.x;

    if (b < LCC_BLOCKS) {
        // [dbuf][g][k][x] y-box-sums, double-buffered (WAR-safe 1-barrier loop)
        __shared__ float ybuf[2][2][8][128];

        int pair = b >> 9;
        int r  = b & 511;
        int y0 = (r & 15) << 3;
        int z0 = ((r >> 4) & 15) << 3;
        int n  = r >> 8;

        const float* gt = pair ? I1  : I0;
        const float* pr = pair ? I1R : I0R;
        double* dst = ws + (pair ? 4 : 1);

        int g  = tid & 1;                      // volume select (lane parity)
        int xp = tid >> 1;                     // x column 0..127
        const float* V = (g ? pr : gt) + (size_t)n * VOL;
        const float gm  = g ? 0.0f : 1.0f;     // masked-accumulate weights
        const float gmi = g ? 1.0f : 0.0f;

        float a1 = 0.f, a2 = 0.f, a3 = 0.f;
        float ps[5][8];                        // z-ring of 2D plane sums
        float cent1[8], cent2[8];              // raw center values, z-2 ring
        float v[12], ybk[8];

        // preload plane z0-2
        {
            int zp = z0 - 2;
            bool zin = (zp >= 0);
            #pragma unroll
            for (int j = 0; j < 12; ++j) {
                int gy = y0 - 2 + j;
                v[j] = (zin && gy >= 0 && gy < 128)
                         ? V[(size_t)zp * PLANE + (size_t)gy * 128 + xp] : 0.0f;
            }
        }

        #pragma unroll
        for (int it = 0; it < 12; ++it) {
            int zp = z0 - 2 + it;

            // (1) issue next-plane prefetch FIRST: in-flight across the
            // whole iteration; first use is next iteration's y-box.
            float vn[12];
            if (it < 11) {
                int zq = zp + 1;
                bool zok = (zq >= 0) && (zq < 128);
                #pragma unroll
                for (int j = 0; j < 12; ++j) {
                    int gy = y0 - 2 + j;
                    vn[j] = (zok && gy >= 0 && gy < 128)
                              ? V[(size_t)zq * PLANE + (size_t)gy * 128 + xp] : 0.0f;
                }
            }

            // (2) y-box-sums (registers) -> LDS buf[it&1]; keep own value in reg
            float* yb = &ybuf[it & 1][g][0][0];
            #pragma unroll
            for (int k = 0; k < 8; ++k) {
                float s = v[k] + v[k+1] + v[k+2] + v[k+3] + v[k+4];
                ybk[k] = s;
                yb[k * 128 + xp] = s;
            }

            bar_lds_only();   // publish ybuf[it&1]; prefetch stays in flight

            // (3) x-box-sum: own value from register, 4 neighbor LDS reads
            //     (exact original add order preserved)
            #pragma unroll
            for (int k = 0; k < 8; ++k) {
                float s = ybk[k];
                if (xp >= 2)   s += yb[k * 128 + xp - 2];
                if (xp >= 1)   s += yb[k * 128 + xp - 1];
                if (xp <= 126) s += yb[k * 128 + xp + 1];
                if (xp <= 125) s += yb[k * 128 + xp + 2];
                ps[it % 5][k] = s;
            }

            // (4) z-box + d; partner's d via intra-wave shfl_xor(1);
            //     masked exact-FMA accumulate (no divergence)
            if (it >= 4) {
                #pragma unroll
                for (int k = 0; k < 8; ++k) {
                    float m = (ps[0][k] + ps[1][k] + ps[2][k] + ps[3][k] + ps[4][k])
                              * (1.0f / 125.0f);
                    float d  = cent2[k] - m;
                    float dp = __shfl_xor(d, 1, 64);
                    float prod = d * dp;
                    float sq   = d * d;
                    a1 += prod * gm;    // gt lane:  dg*dp
                    a2 += sq   * gm;    // gt lane:  dg^2
                    a3 += sq   * gmi;   // pred lane: dp^2
                }
            }

            // shift center ring, advance plane
            #pragma unroll
            for (int k = 0; k < 8; ++k) { cent2[k] = cent1[k]; cent1[k] = v[k + 2]; }
            if (it < 11) {
                #pragma unroll
                for (int j = 0; j < 12; ++j) v[j] = vn[j];
            }
        }
        block_reduce3_atomic((double)a1, (double)a2, (double)a3, dst);

    } else if (b < LCC_BLOCKS + SQ_BLOCKS) {
        // reg field loss numerator: 12,582,912 elems = 3,145,728 float4
        int bid = b - LCC_BLOCKS;
        const float4* A = (const float4*)F0;
        const float4* B = (const float4*)F0g;
        int n4 = 12582912 / 4;
        int idx = bid * 256 + tid;
        int stride = SQ_BLOCKS * 256;
        float acc = 0.f;
        #pragma unroll 4
        for (int i = idx; i < n4; i += stride) {
            float4 xx = A[i], yy = B[i];
            float d0 = yy.x - xx.x, d1 = yy.y - xx.y;
            float d2 = yy.z - xx.z, d3 = yy.w - xx.w;
            acc += (d0 * d0 + d1 * d1) + (d2 * d2 + d3 * d3);
        }
        block_reduce1_atomic((double)acc, &ws[0]);

    } else {
        // tversky: 4,194,304 elems = 1,048,576 float4 per pair
        int bid = b - (LCC_BLOCKS + SQ_BLOCKS);
        int pair = bid >= TV_BLOCKS;
        bid -= pair ? TV_BLOCKS : 0;
        const float4* Gp = (const float4*)(pair ? S1 : S0);
        const float4* Pp = (const float4*)(pair ? S1g : S0g);
        double* dst = ws + (pair ? 9 : 7);
        int n4 = 4194304 / 4;
        int idx = bid * 256 + tid;
        int stride = TV_BLOCKS * 256;
        float asum = 0.f, aprod = 0.f;
        #pragma unroll 4
        for (int i = idx; i < n4; i += stride) {
            float4 xx = Gp[i], yy = Pp[i];
            asum  += (xx.x + yy.x) + (xx.y + yy.y) + (xx.z + yy.z) + (xx.w + yy.w);
            aprod += (xx.x * yy.x + xx.y * yy.y) + (xx.z * yy.z + xx.w * yy.w);
        }
        block_reduce2_atomic((double)asum, (double)aprod, dst);
    }
}

__global__ void finalize_kernel(const double* __restrict__ ws, float* out) {
    if (threadIdx.x == 0 && blockIdx.x == 0) {
        double reg = sqrt(ws[0]) / 12582912.0;

        double num0 = ws[1] * ws[1];
        double den0 = ws[2] * ws[3];
        if (den0 < 1e-5) den0 = 1e-5;
        double l0 = -(1.0 / 4194304.0) * (num0 / den0);

        double num1 = ws[4] * ws[4];
        double den1 = ws[5] * ws[6];
        if (den1 < 1e-5) den1 = 1e-5;
        double l1 = -(1.0 / 4194304.0) * (num1 / den1);

        double td0 = ws[7]; if (td0 < 1e-5) td0 = 1e-5;
        double t0 = -ws[8] / td0;
        double td1 = ws[9]; if (td1 < 1e-5) td1 = 1e-5;
        double t1 = -ws[10] / td1;

        out[0] = (float)(reg + 10.0 * (l0 + l1) + 10.0 * (t0 + t1));
    }
}

// ---------------- launch ----------------

extern "C" void kernel_launch(void* const* d_in, const int* in_sizes, int n_in,
                              void* d_out, int out_size, void* d_ws, size_t ws_size,
                              hipStream_t stream) {
    double* ws = (double*)d_ws;
    float* out = (float*)d_out;

    const float* F0  = (const float*)d_in[0];
    const float* F0g = (const float*)d_in[1];
    const float* I0  = (const float*)d_in[2];
    const float* I0R = (const float*)d_in[3];
    const float* I1  = (const float*)d_in[4];
    const float* I1R = (const float*)d_in[5];
    const float* S0  = (const float*)d_in[6];
    const float* S0g = (const float*)d_in[7];
    const float* S1  = (const float*)d_in[8];
    const float* S1g = (const float*)d_in[9];

    zero_ws_kernel<<<1, 64, 0, stream>>>(ws);
    mega_kernel<<<TOTAL_BLOCKS, 256, 0, stream>>>(F0, F0g, I0, I0R, I1, I1R,
                                                  S0, S0g, S1, S1g, ws);
    finalize_kernel<<<1, 64, 0, stream>>>(ws, out);
}

// Round 3
// 260.757 us; speedup vs baseline: 1.0843x; 1.0843x over previous
//
#include <hip/hip_runtime.h>
#include <math.h>

#define VOL   (128*128*128)   // 2097152 elements per volume
#define PLANE (128*128)       // 16384

// grid partition for mega_kernel
#define LCC_BLOCKS   1024     // 2 pairs x (16 y-tiles x 16 z-tiles x 2 batches)
#define SQ_BLOCKS    1024
#define TV_BLOCKS    256
#define TOTAL_BLOCKS (LCC_BLOCKS + SQ_BLOCKS + 2 * TV_BLOCKS)   // 2560

// ---------------- drain-free barrier ----------------
// LDS release/acquire only: waits lgkmcnt (DS ops) but leaves global-load
// prefetches in flight across the barrier. lgkmcnt(0) before s_barrier also
// covers the WAR hazard: this wave's LDS reads are complete before it passes
// the barrier, so post-barrier overwrites by other waves are safe.
__device__ __forceinline__ void bar_lds_only() {
    asm volatile("s_waitcnt lgkmcnt(0)" ::: "memory");
    __builtin_amdgcn_s_barrier();
}

// ---------------- reduction helpers ----------------

__device__ __forceinline__ double wave_reduce_d(double v) {
    #pragma unroll
    for (int off = 32; off > 0; off >>= 1)
        v += __shfl_down(v, off, 64);
    return v;
}

__device__ __forceinline__ void block_reduce1_atomic(double a, double* dst) {
    __shared__ double s1[4];
    int lane = threadIdx.x & 63;
    int wave = threadIdx.x >> 6;
    a = wave_reduce_d(a);
    if (lane == 0) s1[wave] = a;
    __syncthreads();
    if (threadIdx.x == 0) {
        double A = s1[0] + s1[1] + s1[2] + s1[3];
        atomicAdd(&dst[0], A);
    }
}

__device__ __forceinline__ void block_reduce2_atomic(double a, double b, double* dst) {
    __shared__ double s2[2][4];
    int lane = threadIdx.x & 63;
    int wave = threadIdx.x >> 6;
    a = wave_reduce_d(a);
    b = wave_reduce_d(b);
    if (lane == 0) { s2[0][wave] = a; s2[1][wave] = b; }
    __syncthreads();
    if (threadIdx.x == 0) {
        atomicAdd(&dst[0], s2[0][0] + s2[0][1] + s2[0][2] + s2[0][3]);
        atomicAdd(&dst[1], s2[1][0] + s2[1][1] + s2[1][2] + s2[1][3]);
    }
}

__device__ __forceinline__ void block_reduce3_atomic(double a, double b, double c, double* dst) {
    __shared__ double s3[3][4];
    int lane = threadIdx.x & 63;
    int wave = threadIdx.x >> 6;
    a = wave_reduce_d(a);
    b = wave_reduce_d(b);
    c = wave_reduce_d(c);
    if (lane == 0) { s3[0][wave] = a; s3[1][wave] = b; s3[2][wave] = c; }
    __syncthreads();
    if (threadIdx.x == 0) {
        atomicAdd(&dst[0], s3[0][0] + s3[0][1] + s3[0][2] + s3[0][3]);
        atomicAdd(&dst[1], s3[1][0] + s3[1][1] + s3[1][2] + s3[1][3]);
        atomicAdd(&dst[2], s3[2][0] + s3[2][1] + s3[2][2] + s3[2][3]);
    }
}

// ---------------- ws layout (doubles) ----------------
// [0]      : sum((F_0g - F_0)^2)
// [1..3]   : lcc pair 0: sum(dg*dp), sum(dg^2), sum(dp^2)
// [4..6]   : lcc pair 1
// [7..8]   : tversky 0: sum(g+p), sum(g*p)
// [9..10]  : tversky 1

__global__ void zero_ws_kernel(double* ws) {
    if (threadIdx.x < 16) ws[threadIdx.x] = 0.0;
}

// ---------------- mega kernel ----------------
// Blocks [0,1024): fused LCC (both pairs).  Tile: x=full 128, y=8, z=8.
//   Round-1 structure (g = tid>>7, dbuf exchange, two lgkm-only barriers)
//   + 2-deep plane prefetch: vp[3][12] compile-time ring, each wave keeps
//     ~24 global loads (6 KB) in flight across every iteration instead of
//     a 12-load burst drained at iteration end (MLP was ~5 outstanding
//     load-instrs/CU -> latency-bound at 8% VALUBusy).
//   + XCD-aware block swizzle: XCD (b&7) owns a contiguous chunk of 128
//     logical tiles (16y x 8z slab of one (pair,batch)), so the 2.25x halo
//     re-reads hit that XCD's L2 instead of L3/HBM.
// Blocks [1024,2048): sqdiff (reg_field_loss numerator)
// Blocks [2048,2560): tversky x2

__global__ __launch_bounds__(256) void mega_kernel(
    const float* __restrict__ F0,  const float* __restrict__ F0g,
    const float* __restrict__ I0,  const float* __restrict__ I0R,
    const float* __restrict__ I1,  const float* __restrict__ I1R,
    const float* __restrict__ S0,  const float* __restrict__ S0g,
    const float* __restrict__ S1,  const float* __restrict__ S1g,
    double* __restrict__ ws)
{
    int b = blockIdx.x;
    int tid = threadIdx.x;

    if (b < LCC_BLOCKS) {
        __shared__ float ybuf[2 * 8 * 128];   // [g][k][x] y-box-sums
        __shared__ float dbuf[8 * 128];       // d_pred exchange

        // XCD swizzle: hardware id b -> logical tile L. Bijective on
        // [0,1024): L = (b%8)*128 + b/8. Hardware round-robins XCD = b%8,
        // so each XCD gets logical tiles [xcd*128, (xcd+1)*128).
        int L = (b & 7) * 128 + (b >> 3);

        int pair = L >> 9;
        int r  = L & 511;
        int y0 = (r & 15) << 3;
        int z0 = ((r >> 4) & 15) << 3;
        int n  = r >> 8;

        const float* gt = pair ? I1  : I0;
        const float* pr = pair ? I1R : I0R;
        double* dst = ws + (pair ? 4 : 1);

        int x = tid & 127;
        int g = tid >> 7;                      // wave-uniform (waves 0,1 vs 2,3)
        const float* V = (g ? pr : gt) + (size_t)n * VOL;

        float a1 = 0.f, a2 = 0.f, a3 = 0.f;
        float ps[5][8];                        // z-ring of 2D plane sums
        float cent1[8], cent2[8];              // raw center values, z-2 ring
        float vp[3][12];                       // 3-deep plane ring (2-ahead prefetch)
        float ybk[8];

        float* yb = ybuf + g * 1024;

        // preload planes z0-2 (slot 0) and z0-1 (slot 1): 24 loads in flight
        #pragma unroll
        for (int s = 0; s < 2; ++s) {
            int zp = z0 - 2 + s;               // <= 119, only low guard needed
            bool zin = (zp >= 0);
            #pragma unroll
            for (int j = 0; j < 12; ++j) {
                int gy = y0 - 2 + j;
                vp[s][j] = (zin && gy >= 0 && gy < 128)
                             ? V[(size_t)zp * PLANE + (size_t)gy * 128 + x] : 0.0f;
            }
        }

        #pragma unroll
        for (int it = 0; it < 12; ++it) {
            const int cur = it % 3;            // plane z0-2+it
            const int nxt = (it + 2) % 3;

            // (1) issue 2-ahead prefetch FIRST (plane z0-2+it+2); first use
            // is two iterations away -> full-iteration in-flight window.
            if (it < 10) {
                int zq = z0 + it;              // (z0-2+it)+2 >= 0 always
                bool zok = (zq < 128);
                #pragma unroll
                for (int j = 0; j < 12; ++j) {
                    int gy = y0 - 2 + j;
                    vp[nxt][j] = (zok && gy >= 0 && gy < 128)
                                   ? V[(size_t)zq * PLANE + (size_t)gy * 128 + x] : 0.0f;
                }
            }

            // (2) y-box-sums (registers) -> LDS; keep own value in reg too
            #pragma unroll
            for (int k = 0; k < 8; ++k) {
                float s = vp[cur][k] + vp[cur][k+1] + vp[cur][k+2]
                        + vp[cur][k+3] + vp[cur][k+4];
                ybk[k] = s;
                yb[k * 128 + x] = s;
            }

            bar_lds_only();   // publish ybuf; prefetch stays in flight

            // (3) x-box-sum: own value from register (same value as LDS),
            //     4 neighbor LDS reads, original add order preserved
            #pragma unroll
            for (int k = 0; k < 8; ++k) {
                float s = ybk[k];
                if (x >= 2)   s += yb[k * 128 + x - 2];
                if (x >= 1)   s += yb[k * 128 + x - 1];
                if (x <= 126) s += yb[k * 128 + x + 1];
                if (x <= 125) s += yb[k * 128 + x + 2];
                ps[it % 5][k] = s;
            }

            float d[8];
            if (it >= 4) {
                #pragma unroll
                for (int k = 0; k < 8; ++k) {
                    float m = (ps[0][k] + ps[1][k] + ps[2][k] + ps[3][k] + ps[4][k])
                              * (1.0f / 125.0f);
                    d[k] = cent2[k] - m;       // cent2 holds plane zp-2 raw values
                }
                if (g) {
                    #pragma unroll
                    for (int k = 0; k < 8; ++k) {
                        dbuf[k * 128 + x] = d[k];
                        a3 += d[k] * d[k];
                    }
                }
            }

            bar_lds_only();   // publish dbuf; ybuf reads of this iter drained

            if (it >= 4 && g == 0) {
                #pragma unroll
                for (int k = 0; k < 8; ++k) {
                    float dp = dbuf[k * 128 + x];
                    a1 += d[k] * dp;
                    a2 += d[k] * d[k];
                }
            }

            // shift center ring from the current plane's registers
            #pragma unroll
            for (int k = 0; k < 8; ++k) { cent2[k] = cent1[k]; cent1[k] = vp[cur][k + 2]; }
        }
        block_reduce3_atomic((double)a1, (double)a2, (double)a3, dst);

    } else if (b < LCC_BLOCKS + SQ_BLOCKS) {
        // reg field loss numerator: 12,582,912 elems = 3,145,728 float4
        int bid = b - LCC_BLOCKS;
        const float4* A = (const float4*)F0;
        const float4* B = (const float4*)F0g;
        int n4 = 12582912 / 4;
        int idx = bid * 256 + tid;
        int stride = SQ_BLOCKS * 256;
        float acc = 0.f;
        #pragma unroll 4
        for (int i = idx; i < n4; i += stride) {
            float4 xx = A[i], yy = B[i];
            float d0 = yy.x - xx.x, d1 = yy.y - xx.y;
            float d2 = yy.z - xx.z, d3 = yy.w - xx.w;
            acc += (d0 * d0 + d1 * d1) + (d2 * d2 + d3 * d3);
        }
        block_reduce1_atomic((double)acc, &ws[0]);

    } else {
        // tversky: 4,194,304 elems = 1,048,576 float4 per pair
        int bid = b - (LCC_BLOCKS + SQ_BLOCKS);
        int pair = bid >= TV_BLOCKS;
        bid -= pair ? TV_BLOCKS : 0;
        const float4* Gp = (const float4*)(pair ? S1 : S0);
        const float4* Pp = (const float4*)(pair ? S1g : S0g);
        double* dst = ws + (pair ? 9 : 7);
        int n4 = 4194304 / 4;
        int idx = bid * 256 + tid;
        int stride = TV_BLOCKS * 256;
        float asum = 0.f, aprod = 0.f;
        #pragma unroll 4
        for (int i = idx; i < n4; i += stride) {
            float4 xx = Gp[i], yy = Pp[i];
            asum  += (xx.x + yy.x) + (xx.y + yy.y) + (xx.z + yy.z) + (xx.w + yy.w);
            aprod += (xx.x * yy.x + xx.y * yy.y) + (xx.z * yy.z + xx.w * yy.w);
        }
        block_reduce2_atomic((double)asum, (double)aprod, dst);
    }
}

__global__ void finalize_kernel(const double* __restrict__ ws, float* out) {
    if (threadIdx.x == 0 && blockIdx.x == 0) {
        double reg = sqrt(ws[0]) / 12582912.0;

        double num0 = ws[1] * ws[1];
        double den0 = ws[2] * ws[3];
        if (den0 < 1e-5) den0 = 1e-5;
        double l0 = -(1.0 / 4194304.0) * (num0 / den0);

        double num1 = ws[4] * ws[4];
        double den1 = ws[5] * ws[6];
        if (den1 < 1e-5) den1 = 1e-5;
        double l1 = -(1.0 / 4194304.0) * (num1 / den1);

        double td0 = ws[7]; if (td0 < 1e-5) td0 = 1e-5;
        double t0 = -ws[8] / td0;
        double td1 = ws[9]; if (td1 < 1e-5) td1 = 1e-5;
        double t1 = -ws[10] / td1;

        out[0] = (float)(reg + 10.0 * (l0 + l1) + 10.0 * (t0 + t1));
    }
}

// ---------------- launch ----------------

extern "C" void kernel_launch(void* const* d_in, const int* in_sizes, int n_in,
                              void* d_out, int out_size, void* d_ws, size_t ws_size,
                              hipStream_t stream) {
    double* ws = (double*)d_ws;
    float* out = (float*)d_out;

    const float* F0  = (const float*)d_in[0];
    const float* F0g = (const float*)d_in[1];
    const float* I0  = (const float*)d_in[2];
    const float* I0R = (const float*)d_in[3];
    const float* I1  = (const float*)d_in[4];
    const float* I1R = (const float*)d_in[5];
    const float* S0  = (const float*)d_in[6];
    const float* S0g = (const float*)d_in[7];
    const float* S1  = (const float*)d_in[8];
    const float* S1g = (const float*)d_in[9];

    zero_ws_kernel<<<1, 64, 0, stream>>>(ws);
    mega_kernel<<<TOTAL_BLOCKS, 256, 0, stream>>>(F0, F0g, I0, I0R, I1, I1R,
                                                  S0, S0g, S1, S1g, ws);
    finalize_kernel<<<1, 64, 0, stream>>>(ws, out);
}